// Round 1
// baseline (3466.075 us; speedup 1.0000x reference)
//
#include <hip/hip_runtime.h>

// GATConv: N=50000, NIN=128, H=4, C=16 (HC=64), E=800000 (+N self-loops)
#define NN 50000
#define NIN 128
#define NH 4
#define NC 16
#define HC 64
#define NE 800000
#define NET (NE + NN)
#define NEG_SLOPE 0.2f

// monotone float<->uint mapping for atomicMax on floats
__device__ __forceinline__ unsigned fmap(float f) {
  unsigned u = __float_as_uint(f);
  return (u & 0x80000000u) ? ~u : (u | 0x80000000u);
}
__device__ __forceinline__ float funmap(unsigned u) {
  return __uint_as_float((u & 0x80000000u) ? (u & 0x7FFFFFFFu) : ~u);
}

// init: out = broadcast(bias); m = 0 (== -inf under fmap); denom = 0
__global__ void k_init(const float* __restrict__ bias, float* __restrict__ out,
                       unsigned* __restrict__ m, float* __restrict__ denom) {
  int i = blockIdx.x * blockDim.x + threadIdx.x;
  if (i < NN * HC) out[i] = bias[i & (HC - 1)];
  if (i < NN * NH) { m[i] = 0u; denom[i] = 0.f; }
}

// xw = x @ W  (W staged in LDS), plus per-head attention dots a_src/a_dst.
// block = 256 threads -> 4 rows x 64 cols; grid = NN/4 = 12500
__global__ __launch_bounds__(256) void k_xw(
    const float* __restrict__ x, const float* __restrict__ W,
    const float* __restrict__ att_src, const float* __restrict__ att_dst,
    float* __restrict__ xw, float* __restrict__ a_src, float* __restrict__ a_dst) {
  __shared__ float Ws[NIN][HC];  // 32 KB
  __shared__ float xs[4][NIN];   // 2 KB
  int tid = threadIdx.x;
  for (int i = tid; i < NIN * HC; i += 256) Ws[i >> 6][i & 63] = W[i];
  int row0 = blockIdx.x * 4;
  for (int i = tid; i < 4 * NIN; i += 256) {
    int r = i >> 7, k = i & 127;
    int gr = row0 + r;
    xs[r][k] = (gr < NN) ? x[(size_t)gr * NIN + k] : 0.f;
  }
  __syncthreads();
  int r = tid >> 6, j = tid & 63;  // j == laneid (4 waves of 64)
  int gr = row0 + r;
  float acc = 0.f;
#pragma unroll 8
  for (int k = 0; k < NIN; ++k) acc += xs[r][k] * Ws[k][j];
  int h = j >> 4, c = j & 15;
  float ps = acc * att_src[h * NC + c];
  float pd = acc * att_dst[h * NC + c];
  // reduce over the 16 lanes of each head group
#pragma unroll
  for (int off = 8; off >= 1; off >>= 1) {
    ps += __shfl_xor(ps, off, 64);
    pd += __shfl_xor(pd, off, 64);
  }
  if (gr < NN) {
    xw[(size_t)gr * HC + j] = acc;
    if (c == 0) {
      a_src[gr * NH + h] = ps;
      a_dst[gr * NH + h] = pd;
    }
  }
}

__device__ __forceinline__ void load_edge(const int* __restrict__ ei, int i,
                                          int& s, int& d) {
  if (i < NE) { s = ei[i]; d = ei[NE + i]; }
  else        { s = d = i - NE; }  // self-loop
}

// pass 1: e = leaky_relu(a_src[s] + a_dst[d]); store e; atomicMax m[d][h]
__global__ void k_edge1(const int* __restrict__ ei,
                        const float* __restrict__ a_src,
                        const float* __restrict__ a_dst,
                        float* __restrict__ e_ws, unsigned* __restrict__ m) {
  int i = blockIdx.x * blockDim.x + threadIdx.x;
  if (i >= NET) return;
  int s, d;
  load_edge(ei, i, s, d);
  float4 as4 = *(const float4*)(a_src + (size_t)s * NH);
  float4 ad4 = *(const float4*)(a_dst + (size_t)d * NH);
  float e[4] = {as4.x + ad4.x, as4.y + ad4.y, as4.z + ad4.z, as4.w + ad4.w};
#pragma unroll
  for (int h = 0; h < NH; ++h) {
    e[h] = e[h] > 0.f ? e[h] : NEG_SLOPE * e[h];
    atomicMax(&m[(size_t)d * NH + h], fmap(e[h]));
  }
  *(float4*)(e_ws + (size_t)i * NH) = make_float4(e[0], e[1], e[2], e[3]);
}

// pass 2: denom[d][h] += exp(e - m[d][h])
__global__ void k_edge2(const int* __restrict__ ei,
                        const float* __restrict__ e_ws,
                        const unsigned* __restrict__ m,
                        float* __restrict__ denom) {
  int i = blockIdx.x * blockDim.x + threadIdx.x;
  if (i >= NET) return;
  int s, d;
  load_edge(ei, i, s, d);
  float4 e4 = *(const float4*)(e_ws + (size_t)i * NH);
  uint4 m4 = *(const uint4*)(m + (size_t)d * NH);
  atomicAdd(&denom[(size_t)d * NH + 0], __expf(e4.x - funmap(m4.x)));
  atomicAdd(&denom[(size_t)d * NH + 1], __expf(e4.y - funmap(m4.y)));
  atomicAdd(&denom[(size_t)d * NH + 2], __expf(e4.z - funmap(m4.z)));
  atomicAdd(&denom[(size_t)d * NH + 3], __expf(e4.w - funmap(m4.w)));
}

// pass 3: alpha = exp(e-m)/denom; out[d] += alpha * xw[s]  (thread = edge x head)
__global__ void k_edge3(const int* __restrict__ ei,
                        const float* __restrict__ e_ws,
                        const unsigned* __restrict__ m,
                        const float* __restrict__ denom,
                        const float* __restrict__ xw, float* __restrict__ out) {
  int t = blockIdx.x * blockDim.x + threadIdx.x;
  if (t >= NET * NH) return;
  int i = t >> 2, h = t & 3;
  int s, d;
  load_edge(ei, i, s, d);
  float e = e_ws[(size_t)i * NH + h];
  float mm = funmap(m[(size_t)d * NH + h]);
  float alpha = __expf(e - mm) / (denom[(size_t)d * NH + h] + 1e-16f);
  const float* xs = xw + (size_t)s * HC + h * NC;
  float* od = out + (size_t)d * HC + h * NC;
#pragma unroll
  for (int c0 = 0; c0 < NC; c0 += 4) {
    float4 v = *(const float4*)(xs + c0);
    atomicAdd(od + c0 + 0, alpha * v.x);
    atomicAdd(od + c0 + 1, alpha * v.y);
    atomicAdd(od + c0 + 2, alpha * v.z);
    atomicAdd(od + c0 + 3, alpha * v.w);
  }
}

extern "C" void kernel_launch(void* const* d_in, const int* in_sizes, int n_in,
                              void* d_out, int out_size, void* d_ws, size_t ws_size,
                              hipStream_t stream) {
  const float* x       = (const float*)d_in[0];
  const int*   ei      = (const int*)d_in[1];
  // d_in[2] = edge_attr: ignored by the reference layer
  const float* W       = (const float*)d_in[3];
  const float* att_src = (const float*)d_in[4];
  const float* att_dst = (const float*)d_in[5];
  const float* bias    = (const float*)d_in[6];
  float* out = (float*)d_out;

  char* p = (char*)d_ws;
  float*    xw    = (float*)p;    p += (size_t)NN * HC * 4;   // 12.8 MB
  float*    a_src = (float*)p;    p += (size_t)NN * NH * 4;   // 0.8 MB
  float*    a_dst = (float*)p;    p += (size_t)NN * NH * 4;   // 0.8 MB
  unsigned* mbuf  = (unsigned*)p; p += (size_t)NN * NH * 4;   // 0.8 MB
  float*    denom = (float*)p;    p += (size_t)NN * NH * 4;   // 0.8 MB
  float*    e_ws  = (float*)p;    p += (size_t)NET * NH * 4;  // 13.6 MB

  k_init<<<(NN * HC + 255) / 256, 256, 0, stream>>>(bias, out, mbuf, denom);
  k_xw<<<(NN + 3) / 4, 256, 0, stream>>>(x, W, att_src, att_dst, xw, a_src, a_dst);
  k_edge1<<<(NET + 255) / 256, 256, 0, stream>>>(ei, a_src, a_dst, e_ws, mbuf);
  k_edge2<<<(NET + 255) / 256, 256, 0, stream>>>(ei, e_ws, mbuf, denom);
  k_edge3<<<(NET * NH + 255) / 256, 256, 0, stream>>>(ei, e_ws, mbuf, denom, xw, out);
}

// Round 2
// 336.245 us; speedup vs baseline: 10.3082x; 10.3082x over previous
//
#include <hip/hip_runtime.h>

// GATConv: N=50000, NIN=128, H=4, C=16 (HC=64), E=800000 (+N self-loops)
#define NN 50000
#define NIN 128
#define NH 4
#define NC 16
#define HC 64
#define NE 800000
#define NET (NE + NN)
#define NEG_SLOPE 0.2f

// init deg/cursor to zero
__global__ void k_init(int* __restrict__ deg, int* __restrict__ cursor) {
  int i = blockIdx.x * blockDim.x + threadIdx.x;
  if (i < NN) { deg[i] = 0; cursor[i] = 0; }
}

// xw = x @ W  (W staged in LDS), plus per-head attention dots a_src/a_dst.
// block = 256 threads -> 4 rows x 64 cols; grid = NN/4 = 12500
__global__ __launch_bounds__(256) void k_xw(
    const float* __restrict__ x, const float* __restrict__ W,
    const float* __restrict__ att_src, const float* __restrict__ att_dst,
    float* __restrict__ xw, float* __restrict__ a_src, float* __restrict__ a_dst) {
  __shared__ float Ws[NIN][HC];  // 32 KB
  __shared__ float xs[4][NIN];   // 2 KB
  int tid = threadIdx.x;
  for (int i = tid; i < NIN * HC; i += 256) Ws[i >> 6][i & 63] = W[i];
  int row0 = blockIdx.x * 4;
  for (int i = tid; i < 4 * NIN; i += 256) {
    int r = i >> 7, k = i & 127;
    int gr = row0 + r;
    xs[r][k] = (gr < NN) ? x[(size_t)gr * NIN + k] : 0.f;
  }
  __syncthreads();
  int r = tid >> 6, j = tid & 63;  // j == laneid (4 waves of 64)
  int gr = row0 + r;
  float acc = 0.f;
#pragma unroll 8
  for (int k = 0; k < NIN; ++k) acc += xs[r][k] * Ws[k][j];
  int h = j >> 4, c = j & 15;
  float ps = acc * att_src[h * NC + c];
  float pd = acc * att_dst[h * NC + c];
#pragma unroll
  for (int off = 8; off >= 1; off >>= 1) {
    ps += __shfl_xor(ps, off, 64);
    pd += __shfl_xor(pd, off, 64);
  }
  if (gr < NN) {
    xw[(size_t)gr * HC + j] = acc;
    if (c == 0) {
      a_src[gr * NH + h] = ps;
      a_dst[gr * NH + h] = pd;
    }
  }
}

__device__ __forceinline__ void load_edge(const int* __restrict__ ei, int i,
                                          int& s, int& d) {
  if (i < NE) { s = ei[i]; d = ei[NE + i]; }
  else        { s = d = i - NE; }  // self-loop
}

// histogram of destination degrees
__global__ void k_hist(const int* __restrict__ ei, int* __restrict__ deg) {
  int i = blockIdx.x * blockDim.x + threadIdx.x;
  if (i >= NET) return;
  int s, d;
  load_edge(ei, i, s, d);
  atomicAdd(&deg[d], 1);
}

// single-block exclusive scan of deg[NN] -> ptr[NN+1]
__global__ __launch_bounds__(1024) void k_scan(const int* __restrict__ deg,
                                               int* __restrict__ ptr) {
  __shared__ int buf[1024];
  __shared__ int carry;
  int t = threadIdx.x;
  if (t == 0) carry = 0;
  __syncthreads();
  for (int base = 0; base < NN; base += 1024) {
    int i = base + t;
    int v = (i < NN) ? deg[i] : 0;
    buf[t] = v;
    __syncthreads();
#pragma unroll
    for (int off = 1; off < 1024; off <<= 1) {
      int add = (t >= off) ? buf[t - off] : 0;
      __syncthreads();
      buf[t] += add;
      __syncthreads();
    }
    if (i < NN) ptr[i] = carry + buf[t] - v;  // exclusive
    __syncthreads();
    if (t == 1023) carry += buf[1023];
    __syncthreads();
  }
  if (t == 0) ptr[NN] = carry;
}

// scatter src ids into dst-sorted order
__global__ void k_scatter(const int* __restrict__ ei, const int* __restrict__ ptr,
                          int* __restrict__ cursor, int* __restrict__ ss) {
  int i = blockIdx.x * blockDim.x + threadIdx.x;
  if (i >= NET) return;
  int s, d;
  load_edge(ei, i, s, d);
  int pos = atomicAdd(&cursor[d], 1);
  ss[ptr[d] + pos] = s;
}

// one wave per destination node: segment softmax + register accumulation
__global__ __launch_bounds__(256) void k_gat(
    const int* __restrict__ ptr, const int* __restrict__ ss,
    const float* __restrict__ a_src, const float* __restrict__ a_dst,
    const float* __restrict__ xw, const float* __restrict__ bias,
    float* __restrict__ out) {
  int tid = threadIdx.x;
  int wv = tid >> 6, j = tid & 63;
  int d = blockIdx.x * 4 + wv;
  if (d >= NN) return;
  int base = ptr[d], deg = ptr[d + 1] - base;

  // phase A: 16 lanes per head (head = j&3), strided over edges
  int h1 = j & 3;
  float adr = a_dst[(size_t)d * NH + h1];
  float mx = -1e30f;
  for (int i = j >> 2; i < deg; i += 16) {
    int s = ss[base + i];
    float e = a_src[(size_t)s * NH + h1] + adr;
    e = e > 0.f ? e : NEG_SLOPE * e;
    mx = fmaxf(mx, e);
  }
#pragma unroll
  for (int off = 4; off < 64; off <<= 1) mx = fmaxf(mx, __shfl_xor(mx, off, 64));
  float sum = 0.f;
  for (int i = j >> 2; i < deg; i += 16) {
    int s = ss[base + i];
    float e = a_src[(size_t)s * NH + h1] + adr;
    e = e > 0.f ? e : NEG_SLOPE * e;
    sum += __expf(e - mx);
  }
#pragma unroll
  for (int off = 4; off < 64; off <<= 1) sum += __shfl_xor(sum, off, 64);

  // phase B: lane j = output channel; h = j>>4
  int h = j >> 4;
  float m_b = __shfl(mx, h, 64);
  float rden = 1.f / (__shfl(sum, h, 64) + 1e-16f);
  float ad2 = a_dst[(size_t)d * NH + h];
  float acc = 0.f;
  for (int i = 0; i < deg; ++i) {
    int s = ss[base + i];
    float e = a_src[(size_t)s * NH + h] + ad2;
    e = e > 0.f ? e : NEG_SLOPE * e;
    acc += __expf(e - m_b) * rden * xw[(size_t)s * HC + j];
  }
  out[(size_t)d * HC + j] = acc + bias[j];
}

extern "C" void kernel_launch(void* const* d_in, const int* in_sizes, int n_in,
                              void* d_out, int out_size, void* d_ws, size_t ws_size,
                              hipStream_t stream) {
  const float* x       = (const float*)d_in[0];
  const int*   ei      = (const int*)d_in[1];
  // d_in[2] = edge_attr: ignored by the reference layer
  const float* W       = (const float*)d_in[3];
  const float* att_src = (const float*)d_in[4];
  const float* att_dst = (const float*)d_in[5];
  const float* bias    = (const float*)d_in[6];
  float* out = (float*)d_out;

  char* p = (char*)d_ws;
  float* xw     = (float*)p; p += (size_t)NN * HC * 4;   // 12.8 MB
  float* a_src  = (float*)p; p += (size_t)NN * NH * 4;   // 0.8 MB
  float* a_dst  = (float*)p; p += (size_t)NN * NH * 4;   // 0.8 MB
  int*   deg    = (int*)p;   p += (size_t)NN * 4;        // 0.2 MB
  int*   ptr    = (int*)p;   p += (size_t)(NN + 1) * 4;  // 0.2 MB
  int*   cursor = (int*)p;   p += (size_t)NN * 4;        // 0.2 MB
  int*   ss     = (int*)p;   p += (size_t)NET * 4;       // 3.4 MB

  k_init<<<(NN + 255) / 256, 256, 0, stream>>>(deg, cursor);
  k_xw<<<(NN + 3) / 4, 256, 0, stream>>>(x, W, att_src, att_dst, xw, a_src, a_dst);
  k_hist<<<(NET + 255) / 256, 256, 0, stream>>>(ei, deg);
  k_scan<<<1, 1024, 0, stream>>>(deg, ptr);
  k_scatter<<<(NET + 255) / 256, 256, 0, stream>>>(ei, ptr, cursor, ss);
  k_gat<<<(NN + 3) / 4, 256, 0, stream>>>(ptr, ss, a_src, a_dst, xw, bias, out);
}

// Round 3
// 306.448 us; speedup vs baseline: 11.3105x; 1.0972x over previous
//
#include <hip/hip_runtime.h>

// GATConv: N=50000, NIN=128, H=4, C=16 (HC=64), E=800000 (+N self-loops)
#define NN 50000
#define NIN 128
#define NH 4
#define NC 16
#define HC 64
#define NE 800000
#define NET (NE + NN)
#define NEG_SLOPE 0.2f

// init deg/cursor to zero
__global__ void k_init(int* __restrict__ deg, int* __restrict__ cursor) {
  int i = blockIdx.x * blockDim.x + threadIdx.x;
  if (i < NN) { deg[i] = 0; cursor[i] = 0; }
}

// xw = x @ W, 16 rows per block (4 rows per thread), plus attention dots.
// block = 256 threads (4 waves x 64 cols); grid = NN/16 = 3125
__global__ __launch_bounds__(256) void k_xw(
    const float* __restrict__ x, const float* __restrict__ W,
    const float* __restrict__ att_src, const float* __restrict__ att_dst,
    float* __restrict__ xw, float* __restrict__ a_src, float* __restrict__ a_dst) {
  __shared__ float Ws[NIN][HC];   // 32 KB
  __shared__ float xs[16][NIN];   // 8 KB
  int tid = threadIdx.x;
  int row0 = blockIdx.x * 16;
  {
    const float4* wsrc = (const float4*)W;
    float4* wdst = (float4*)&Ws[0][0];
    for (int i = tid; i < NIN * HC / 4; i += 256) wdst[i] = wsrc[i];
    const float4* xsrc = (const float4*)(x + (size_t)row0 * NIN);
    float4* xdst = (float4*)&xs[0][0];
    for (int i = tid; i < 16 * NIN / 4; i += 256) xdst[i] = xsrc[i];
  }
  __syncthreads();
  int j = tid & 63;
  int r4 = (tid >> 6) * 4;  // this wave's 4 rows
  float acc0 = 0.f, acc1 = 0.f, acc2 = 0.f, acc3 = 0.f;
#pragma unroll
  for (int k0 = 0; k0 < NIN; k0 += 4) {
    float4 x0 = *(const float4*)&xs[r4 + 0][k0];
    float4 x1 = *(const float4*)&xs[r4 + 1][k0];
    float4 x2 = *(const float4*)&xs[r4 + 2][k0];
    float4 x3 = *(const float4*)&xs[r4 + 3][k0];
    float w0 = Ws[k0 + 0][j], w1 = Ws[k0 + 1][j];
    float w2 = Ws[k0 + 2][j], w3 = Ws[k0 + 3][j];
    acc0 += x0.x * w0 + x0.y * w1 + x0.z * w2 + x0.w * w3;
    acc1 += x1.x * w0 + x1.y * w1 + x1.z * w2 + x1.w * w3;
    acc2 += x2.x * w0 + x2.y * w1 + x2.z * w2 + x2.w * w3;
    acc3 += x3.x * w0 + x3.y * w1 + x3.z * w2 + x3.w * w3;
  }
  int h = j >> 4, c = j & 15;
  float as = att_src[h * NC + c], ad = att_dst[h * NC + c];
  float accs[4] = {acc0, acc1, acc2, acc3};
#pragma unroll
  for (int q = 0; q < 4; ++q) {
    int gr = row0 + r4 + q;
    float ps = accs[q] * as, pd = accs[q] * ad;
#pragma unroll
    for (int off = 8; off >= 1; off >>= 1) {
      ps += __shfl_xor(ps, off, 64);
      pd += __shfl_xor(pd, off, 64);
    }
    xw[(size_t)gr * HC + j] = accs[q];
    if (c == 0) {
      a_src[gr * NH + h] = ps;
      a_dst[gr * NH + h] = pd;
    }
  }
}

// histogram of destination degrees (dst only)
__global__ void k_hist(const int* __restrict__ ei, int* __restrict__ deg) {
  int i = blockIdx.x * blockDim.x + threadIdx.x;
  if (i >= NET) return;
  int d = (i < NE) ? ei[NE + i] : i - NE;
  atomicAdd(&deg[d], 1);
}

// single-block chunked exclusive scan of deg[NN] -> ptr[NN+1]
#define CHUNK 49  // ceil(50000/1024)
__global__ __launch_bounds__(1024) void k_scan(const int* __restrict__ deg,
                                               int* __restrict__ ptr) {
  __shared__ int buf[1024];
  int t = threadIdx.x;
  int lo = t * CHUNK;
  int hi = min(lo + CHUNK, NN);
  int s = 0;
  for (int i = lo; i < hi; ++i) s += deg[i];
  buf[t] = s;
  __syncthreads();
#pragma unroll
  for (int off = 1; off < 1024; off <<= 1) {
    int add = (t >= off) ? buf[t - off] : 0;
    __syncthreads();
    buf[t] += add;
    __syncthreads();
  }
  int run = buf[t] - s;  // exclusive prefix of this chunk
  for (int i = lo; i < hi; ++i) { ptr[i] = run; run += deg[i]; }
  if (t == 1023) ptr[NN] = buf[1023];
}

// scatter src ids into dst-sorted order
__global__ void k_scatter(const int* __restrict__ ei, const int* __restrict__ ptr,
                          int* __restrict__ cursor, int* __restrict__ ss) {
  int i = blockIdx.x * blockDim.x + threadIdx.x;
  if (i >= NET) return;
  int s, d;
  if (i < NE) { s = ei[i]; d = ei[NE + i]; }
  else        { s = d = i - NE; }
  int pos = atomicAdd(&cursor[d], 1);
  ss[ptr[d] + pos] = s;
}

// one wave per destination node: online segment softmax + register accumulation
__global__ __launch_bounds__(256) void k_gat(
    const int* __restrict__ ptr, const int* __restrict__ ss,
    const float* __restrict__ a_src, const float* __restrict__ a_dst,
    const float* __restrict__ xw, const float* __restrict__ bias,
    float* __restrict__ out) {
  int tid = threadIdx.x;
  int wv = tid >> 6, j = tid & 63;
  int d = blockIdx.x * 4 + wv;
  if (d >= NN) return;
  int base = ptr[d], deg = ptr[d + 1] - base;

  // phase A: online (max,sum) per head; head h1 = j&3, 16 lane-groups stride edges
  int h1 = j & 3;
  float adr = a_dst[(size_t)d * NH + h1];
  float m = -1e30f, sum = 0.f;
  for (int i = j >> 2; i < deg; i += 16) {
    int s = ss[base + i];
    float e = a_src[(size_t)s * NH + h1] + adr;
    e = e > 0.f ? e : NEG_SLOPE * e;
    float mn = fmaxf(m, e);
    sum = sum * __expf(m - mn) + __expf(e - mn);
    m = mn;
  }
#pragma unroll
  for (int off = 4; off < 64; off <<= 1) {
    float mo = __shfl_xor(m, off, 64);
    float so = __shfl_xor(sum, off, 64);
    float mn = fmaxf(m, mo);
    sum = sum * __expf(m - mn) + so * __expf(mo - mn);
    m = mn;
  }
  float rden = 1.f / (sum + 1e-16f);  // per-lane: head j&3

  // phase B: lanes compute alpha for 16 edges x 4 heads in parallel,
  // then unrolled 16-step gather-fma (lane j = output channel, head j>>4)
  int hb = j >> 4;
  float acc = 0.f;
  int i0 = 0;
  for (; i0 + 16 <= deg; i0 += 16) {
    int s_j = ss[base + i0 + (j >> 2)];
    float e = a_src[(size_t)s_j * NH + h1] + adr;
    e = e > 0.f ? e : NEG_SLOPE * e;
    float al = __expf(e - m) * rden;
#pragma unroll
    for (int k = 0; k < 16; ++k) {
      int s = __shfl(s_j, k * 4, 64);
      float alpha = __shfl(al, k * 4 + hb, 64);
      acc += alpha * xw[(size_t)s * HC + j];
    }
  }
  int rem = deg - i0;
  if (rem > 0) {
    int ii = i0 + (j >> 2);
    int s_j = ss[base + (ii < deg ? ii : deg - 1)];
    float e = a_src[(size_t)s_j * NH + h1] + adr;
    e = e > 0.f ? e : NEG_SLOPE * e;
    float al = (ii < deg) ? __expf(e - m) * rden : 0.f;
    for (int k = 0; k < rem; ++k) {
      int s = __shfl(s_j, k * 4, 64);
      float alpha = __shfl(al, k * 4 + hb, 64);
      acc += alpha * xw[(size_t)s * HC + j];
    }
  }
  out[(size_t)d * HC + j] = acc + bias[j];
}

extern "C" void kernel_launch(void* const* d_in, const int* in_sizes, int n_in,
                              void* d_out, int out_size, void* d_ws, size_t ws_size,
                              hipStream_t stream) {
  const float* x       = (const float*)d_in[0];
  const int*   ei      = (const int*)d_in[1];
  // d_in[2] = edge_attr: ignored by the reference layer
  const float* W       = (const float*)d_in[3];
  const float* att_src = (const float*)d_in[4];
  const float* att_dst = (const float*)d_in[5];
  const float* bias    = (const float*)d_in[6];
  float* out = (float*)d_out;

  char* p = (char*)d_ws;
  float* xw     = (float*)p; p += (size_t)NN * HC * 4;   // 12.8 MB
  float* a_src  = (float*)p; p += (size_t)NN * NH * 4;   // 0.8 MB
  float* a_dst  = (float*)p; p += (size_t)NN * NH * 4;   // 0.8 MB
  int*   deg    = (int*)p;   p += (size_t)NN * 4;        // 0.2 MB
  int*   ptr    = (int*)p;   p += (size_t)(NN + 1) * 4;  // 0.2 MB
  int*   cursor = (int*)p;   p += (size_t)NN * 4;        // 0.2 MB
  int*   ss     = (int*)p;   p += (size_t)NET * 4;       // 3.4 MB

  k_init<<<(NN + 255) / 256, 256, 0, stream>>>(deg, cursor);
  k_xw<<<NN / 16, 256, 0, stream>>>(x, W, att_src, att_dst, xw, a_src, a_dst);
  k_hist<<<(NET + 255) / 256, 256, 0, stream>>>(ei, deg);
  k_scan<<<1, 1024, 0, stream>>>(deg, ptr);
  k_scatter<<<(NET + 255) / 256, 256, 0, stream>>>(ei, ptr, cursor, ss);
  k_gat<<<(NN + 3) / 4, 256, 0, stream>>>(ptr, ss, a_src, a_dst, xw, bias, out);
}

// Round 4
// 259.552 us; speedup vs baseline: 13.3541x; 1.1807x over previous
//
#include <hip/hip_runtime.h>

// GATConv: N=50000, NIN=128, H=4, C=16 (HC=64), E=800000 (+N self-loops)
#define NN 50000
#define NIN 128
#define NH 4
#define NC 16
#define HC 64
#define NE 800000
#define NET (NE + NN)
#define NEG_SLOPE 0.2f

// init deg/cursor to zero
__global__ void k_init(int* __restrict__ deg, int* __restrict__ cursor) {
  int i = blockIdx.x * blockDim.x + threadIdx.x;
  if (i < NN) { deg[i] = 0; cursor[i] = 0; }
}

// xw = x @ W, 16 rows per block (4 rows per thread), plus attention dots.
// block = 256 threads (4 waves x 64 cols); grid = NN/16 = 3125
// __launch_bounds__(256,4): cap VGPR<=128 — full unroll previously hit 256 VGPR
// and 10% occupancy (latency-bound, 103us). LDS 40KB caps 4 blocks/CU anyway.
__global__ __launch_bounds__(256, 4) void k_xw(
    const float* __restrict__ x, const float* __restrict__ W,
    const float* __restrict__ att_src, const float* __restrict__ att_dst,
    float* __restrict__ xw, float* __restrict__ a_src, float* __restrict__ a_dst) {
  __shared__ float Ws[NIN][HC];   // 32 KB
  __shared__ float xs[16][NIN];   // 8 KB
  int tid = threadIdx.x;
  int row0 = blockIdx.x * 16;
  {
    const float4* wsrc = (const float4*)W;
    float4* wdst = (float4*)&Ws[0][0];
    for (int i = tid; i < NIN * HC / 4; i += 256) wdst[i] = wsrc[i];
    const float4* xsrc = (const float4*)(x + (size_t)row0 * NIN);
    float4* xdst = (float4*)&xs[0][0];
    for (int i = tid; i < 16 * NIN / 4; i += 256) xdst[i] = xsrc[i];
  }
  __syncthreads();
  int j = tid & 63;
  int r4 = (tid >> 6) * 4;  // this wave's 4 rows
  float acc0 = 0.f, acc1 = 0.f, acc2 = 0.f, acc3 = 0.f;
#pragma unroll 2
  for (int k0 = 0; k0 < NIN; k0 += 4) {
    float4 x0 = *(const float4*)&xs[r4 + 0][k0];
    float4 x1 = *(const float4*)&xs[r4 + 1][k0];
    float4 x2 = *(const float4*)&xs[r4 + 2][k0];
    float4 x3 = *(const float4*)&xs[r4 + 3][k0];
    float w0 = Ws[k0 + 0][j], w1 = Ws[k0 + 1][j];
    float w2 = Ws[k0 + 2][j], w3 = Ws[k0 + 3][j];
    acc0 += x0.x * w0 + x0.y * w1 + x0.z * w2 + x0.w * w3;
    acc1 += x1.x * w0 + x1.y * w1 + x1.z * w2 + x1.w * w3;
    acc2 += x2.x * w0 + x2.y * w1 + x2.z * w2 + x2.w * w3;
    acc3 += x3.x * w0 + x3.y * w1 + x3.z * w2 + x3.w * w3;
  }
  int h = j >> 4, c = j & 15;
  float as = att_src[h * NC + c], ad = att_dst[h * NC + c];
  float accs[4] = {acc0, acc1, acc2, acc3};
#pragma unroll
  for (int q = 0; q < 4; ++q) {
    int gr = row0 + r4 + q;
    float ps = accs[q] * as, pd = accs[q] * ad;
#pragma unroll
    for (int off = 8; off >= 1; off >>= 1) {
      ps += __shfl_xor(ps, off, 64);
      pd += __shfl_xor(pd, off, 64);
    }
    xw[(size_t)gr * HC + j] = accs[q];
    if (c == 0) {
      a_src[gr * NH + h] = ps;
      a_dst[gr * NH + h] = pd;
    }
  }
}

// histogram of destination degrees (dst only)
__global__ void k_hist(const int* __restrict__ ei, int* __restrict__ deg) {
  int i = blockIdx.x * blockDim.x + threadIdx.x;
  if (i >= NET) return;
  int d = (i < NE) ? ei[NE + i] : i - NE;
  atomicAdd(&deg[d], 1);
}

// single-block chunked exclusive scan of deg[NN] -> ptr[NN+1]
#define CHUNK 49  // ceil(50000/1024)
__global__ __launch_bounds__(1024) void k_scan(const int* __restrict__ deg,
                                               int* __restrict__ ptr) {
  __shared__ int buf[1024];
  int t = threadIdx.x;
  int lo = t * CHUNK;
  int hi = min(lo + CHUNK, NN);
  int s = 0;
  for (int i = lo; i < hi; ++i) s += deg[i];
  buf[t] = s;
  __syncthreads();
#pragma unroll
  for (int off = 1; off < 1024; off <<= 1) {
    int add = (t >= off) ? buf[t - off] : 0;
    __syncthreads();
    buf[t] += add;
    __syncthreads();
  }
  int run = buf[t] - s;  // exclusive prefix of this chunk
  for (int i = lo; i < hi; ++i) { ptr[i] = run; run += deg[i]; }
  if (t == 1023) ptr[NN] = buf[1023];
}

// scatter src ids into dst-sorted order
__global__ void k_scatter(const int* __restrict__ ei, const int* __restrict__ ptr,
                          int* __restrict__ cursor, int* __restrict__ ss) {
  int i = blockIdx.x * blockDim.x + threadIdx.x;
  if (i >= NET) return;
  int s, d;
  if (i < NE) { s = ei[i]; d = ei[NE + i]; }
  else        { s = d = i - NE; }
  int pos = atomicAdd(&cursor[d], 1);
  ss[ptr[d] + pos] = s;
}

// one wave per destination node: online segment softmax + register accumulation
__global__ __launch_bounds__(256) void k_gat(
    const int* __restrict__ ptr, const int* __restrict__ ss,
    const float* __restrict__ a_src, const float* __restrict__ a_dst,
    const float* __restrict__ xw, const float* __restrict__ bias,
    float* __restrict__ out) {
  int tid = threadIdx.x;
  int wv = tid >> 6, j = tid & 63;
  int d = blockIdx.x * 4 + wv;
  if (d >= NN) return;
  int base = ptr[d], deg = ptr[d + 1] - base;

  // phase A: online (max,sum) per head; head h1 = j&3, 16 lane-groups stride edges
  int h1 = j & 3;
  float adr = a_dst[(size_t)d * NH + h1];
  float m = -1e30f, sum = 0.f;
  for (int i = j >> 2; i < deg; i += 16) {
    int s = ss[base + i];
    float e = a_src[(size_t)s * NH + h1] + adr;
    e = e > 0.f ? e : NEG_SLOPE * e;
    float mn = fmaxf(m, e);
    sum = sum * __expf(m - mn) + __expf(e - mn);
    m = mn;
  }
#pragma unroll
  for (int off = 4; off < 64; off <<= 1) {
    float mo = __shfl_xor(m, off, 64);
    float so = __shfl_xor(sum, off, 64);
    float mn = fmaxf(m, mo);
    sum = sum * __expf(m - mn) + so * __expf(mo - mn);
    m = mn;
  }
  float rden = 1.f / (sum + 1e-16f);  // per-lane: head j&3

  // phase B: lanes compute alpha for 16 edges x 4 heads in parallel,
  // then unrolled 16-step gather-fma (lane j = output channel, head j>>4)
  int hb = j >> 4;
  float acc = 0.f;
  int i0 = 0;
  for (; i0 + 16 <= deg; i0 += 16) {
    int s_j = ss[base + i0 + (j >> 2)];
    float e = a_src[(size_t)s_j * NH + h1] + adr;
    e = e > 0.f ? e : NEG_SLOPE * e;
    float al = __expf(e - m) * rden;
#pragma unroll
    for (int k = 0; k < 16; ++k) {
      int s = __shfl(s_j, k * 4, 64);
      float alpha = __shfl(al, k * 4 + hb, 64);
      acc += alpha * xw[(size_t)s * HC + j];
    }
  }
  int rem = deg - i0;
  if (rem > 0) {
    int ii = i0 + (j >> 2);
    int s_j = ss[base + (ii < deg ? ii : deg - 1)];
    float e = a_src[(size_t)s_j * NH + h1] + adr;
    e = e > 0.f ? e : NEG_SLOPE * e;
    float al = (ii < deg) ? __expf(e - m) * rden : 0.f;
    for (int k = 0; k < rem; ++k) {
      int s = __shfl(s_j, k * 4, 64);
      float alpha = __shfl(al, k * 4 + hb, 64);
      acc += alpha * xw[(size_t)s * HC + j];
    }
  }
  out[(size_t)d * HC + j] = acc + bias[j];
}

extern "C" void kernel_launch(void* const* d_in, const int* in_sizes, int n_in,
                              void* d_out, int out_size, void* d_ws, size_t ws_size,
                              hipStream_t stream) {
  const float* x       = (const float*)d_in[0];
  const int*   ei      = (const int*)d_in[1];
  // d_in[2] = edge_attr: ignored by the reference layer
  const float* W       = (const float*)d_in[3];
  const float* att_src = (const float*)d_in[4];
  const float* att_dst = (const float*)d_in[5];
  const float* bias    = (const float*)d_in[6];
  float* out = (float*)d_out;

  char* p = (char*)d_ws;
  float* xw     = (float*)p; p += (size_t)NN * HC * 4;   // 12.8 MB
  float* a_src  = (float*)p; p += (size_t)NN * NH * 4;   // 0.8 MB
  float* a_dst  = (float*)p; p += (size_t)NN * NH * 4;   // 0.8 MB
  int*   deg    = (int*)p;   p += (size_t)NN * 4;        // 0.2 MB
  int*   ptr    = (int*)p;   p += (size_t)(NN + 1) * 4;  // 0.2 MB
  int*   cursor = (int*)p;   p += (size_t)NN * 4;        // 0.2 MB
  int*   ss     = (int*)p;   p += (size_t)NET * 4;       // 3.4 MB

  k_init<<<(NN + 255) / 256, 256, 0, stream>>>(deg, cursor);
  k_xw<<<NN / 16, 256, 0, stream>>>(x, W, att_src, att_dst, xw, a_src, a_dst);
  k_hist<<<(NET + 255) / 256, 256, 0, stream>>>(ei, deg);
  k_scan<<<1, 1024, 0, stream>>>(deg, ptr);
  k_scatter<<<(NET + 255) / 256, 256, 0, stream>>>(ei, ptr, cursor, ss);
  k_gat<<<(NN + 3) / 4, 256, 0, stream>>>(ptr, ss, a_src, a_dst, xw, bias, out);
}

// Round 5
// 189.113 us; speedup vs baseline: 18.3281x; 1.3725x over previous
//
#include <hip/hip_runtime.h>

// GATConv: N=50000, NIN=128, H=4, C=16 (HC=64), E=800000 (+N self-loops)
#define NN 50000
#define NIN 128
#define NH 4
#define NC 16
#define HC 64
#define NE 800000
#define NET (NE + NN)
#define NEG_SLOPE 0.2f
#define NBLK ((NN + 1023) / 1024)  // 49 scan blocks

// init deg/cursor to zero
__global__ void k_init(int* __restrict__ deg, int* __restrict__ cursor) {
  int i = blockIdx.x * blockDim.x + threadIdx.x;
  if (i < NN) { deg[i] = 0; cursor[i] = 0; }
}

// xw = x @ W, 16 rows per block (4 rows per thread), plus attention dots.
__global__ __launch_bounds__(256, 4) void k_xw(
    const float* __restrict__ x, const float* __restrict__ W,
    const float* __restrict__ att_src, const float* __restrict__ att_dst,
    float* __restrict__ xw, float* __restrict__ a_src, float* __restrict__ a_dst) {
  __shared__ float Ws[NIN][HC];   // 32 KB
  __shared__ float xs[16][NIN];   // 8 KB
  int tid = threadIdx.x;
  int row0 = blockIdx.x * 16;
  {
    const float4* wsrc = (const float4*)W;
    float4* wdst = (float4*)&Ws[0][0];
    for (int i = tid; i < NIN * HC / 4; i += 256) wdst[i] = wsrc[i];
    const float4* xsrc = (const float4*)(x + (size_t)row0 * NIN);
    float4* xdst = (float4*)&xs[0][0];
    for (int i = tid; i < 16 * NIN / 4; i += 256) xdst[i] = xsrc[i];
  }
  __syncthreads();
  int j = tid & 63;
  int r4 = (tid >> 6) * 4;  // this wave's 4 rows
  float acc0 = 0.f, acc1 = 0.f, acc2 = 0.f, acc3 = 0.f;
#pragma unroll 2
  for (int k0 = 0; k0 < NIN; k0 += 4) {
    float4 x0 = *(const float4*)&xs[r4 + 0][k0];
    float4 x1 = *(const float4*)&xs[r4 + 1][k0];
    float4 x2 = *(const float4*)&xs[r4 + 2][k0];
    float4 x3 = *(const float4*)&xs[r4 + 3][k0];
    float w0 = Ws[k0 + 0][j], w1 = Ws[k0 + 1][j];
    float w2 = Ws[k0 + 2][j], w3 = Ws[k0 + 3][j];
    acc0 += x0.x * w0 + x0.y * w1 + x0.z * w2 + x0.w * w3;
    acc1 += x1.x * w0 + x1.y * w1 + x1.z * w2 + x1.w * w3;
    acc2 += x2.x * w0 + x2.y * w1 + x2.z * w2 + x2.w * w3;
    acc3 += x3.x * w0 + x3.y * w1 + x3.z * w2 + x3.w * w3;
  }
  int h = j >> 4, c = j & 15;
  float as = att_src[h * NC + c], ad = att_dst[h * NC + c];
  float accs[4] = {acc0, acc1, acc2, acc3};
#pragma unroll
  for (int q = 0; q < 4; ++q) {
    int gr = row0 + r4 + q;
    float ps = accs[q] * as, pd = accs[q] * ad;
#pragma unroll
    for (int off = 8; off >= 1; off >>= 1) {
      ps += __shfl_xor(ps, off, 64);
      pd += __shfl_xor(pd, off, 64);
    }
    xw[(size_t)gr * HC + j] = accs[q];
    if (c == 0) {
      a_src[gr * NH + h] = ps;
      a_dst[gr * NH + h] = pd;
    }
  }
}

// histogram of destination degrees (dst only)
__global__ void k_hist(const int* __restrict__ ei, int* __restrict__ deg) {
  int i = blockIdx.x * blockDim.x + threadIdx.x;
  if (i >= NET) return;
  int d = (i < NE) ? ei[NE + i] : i - NE;
  atomicAdd(&deg[d], 1);
}

// hierarchical scan, level 1: per-block exclusive prefix + block totals
__global__ __launch_bounds__(1024) void k_scan1(const int* __restrict__ deg,
                                                int* __restrict__ ptr,
                                                int* __restrict__ bsum) {
  int t = threadIdx.x, b = blockIdx.x;
  int i = b * 1024 + t;
  int v = (i < NN) ? deg[i] : 0;
  int lane = t & 63, wid = t >> 6;
  int sv = v;
#pragma unroll
  for (int off = 1; off < 64; off <<= 1) {
    int n = __shfl_up(sv, off, 64);
    if (lane >= off) sv += n;
  }
  __shared__ int wsum[16];
  if (lane == 63) wsum[wid] = sv;
  __syncthreads();
  if (t < 16) {
    int w = wsum[t];
    int sw = w;
#pragma unroll
    for (int off = 1; off < 16; off <<= 1) {
      int n = __shfl_up(sw, off, 64);
      if (t >= off) sw += n;
    }
    wsum[t] = sw - w;  // exclusive wave offset
    if (t == 15) bsum[b] = sw;  // block total
  }
  __syncthreads();
  if (i < NN) ptr[i] = wsum[wid] + sv - v;
}

// level 2: add block offsets (wave 0 scans the 49 block totals)
__global__ __launch_bounds__(1024) void k_scan2(const int* __restrict__ bsum,
                                                int* __restrict__ ptr) {
  int t = threadIdx.x, b = blockIdx.x;
  __shared__ int off_s, tot_s;
  if (t < 64) {
    int v = (t < NBLK) ? bsum[t] : 0;
    int sv = v;
#pragma unroll
    for (int off = 1; off < 64; off <<= 1) {
      int n = __shfl_up(sv, off, 64);
      if (t >= off) sv += n;
    }
    if (t == b) off_s = sv - v;          // exclusive prefix for this block
    if (t == NBLK - 1) tot_s = sv;       // grand total
  }
  __syncthreads();
  int i = b * 1024 + t;
  if (i < NN) ptr[i] += off_s;
  if (i == NN - 1) ptr[NN] = tot_s;
}

// scatter src ids into dst-sorted order
__global__ void k_scatter(const int* __restrict__ ei, const int* __restrict__ ptr,
                          int* __restrict__ cursor, int* __restrict__ ss) {
  int i = blockIdx.x * blockDim.x + threadIdx.x;
  if (i >= NET) return;
  int s, d;
  if (i < NE) { s = ei[i]; d = ei[NE + i]; }
  else        { s = d = i - NE; }
  int pos = atomicAdd(&cursor[d], 1);
  ss[ptr[d] + pos] = s;
}

// one wave per destination node: online segment softmax + register accumulation
__global__ __launch_bounds__(256) void k_gat(
    const int* __restrict__ ptr, const int* __restrict__ ss,
    const float* __restrict__ a_src, const float* __restrict__ a_dst,
    const float* __restrict__ xw, const float* __restrict__ bias,
    float* __restrict__ out) {
  int tid = threadIdx.x;
  int wv = tid >> 6, j = tid & 63;
  int d = blockIdx.x * 4 + wv;
  if (d >= NN) return;
  int base = ptr[d], deg = ptr[d + 1] - base;

  // phase A: online (max,sum) per head; head h1 = j&3, 16 lane-groups stride edges
  int h1 = j & 3;
  float adr = a_dst[(size_t)d * NH + h1];
  float m = -1e30f, sum = 0.f;
  for (int i = j >> 2; i < deg; i += 16) {
    int s = ss[base + i];
    float e = a_src[(size_t)s * NH + h1] + adr;
    e = e > 0.f ? e : NEG_SLOPE * e;
    float mn = fmaxf(m, e);
    sum = sum * __expf(m - mn) + __expf(e - mn);
    m = mn;
  }
#pragma unroll
  for (int off = 4; off < 64; off <<= 1) {
    float mo = __shfl_xor(m, off, 64);
    float so = __shfl_xor(sum, off, 64);
    float mn = fmaxf(m, mo);
    sum = sum * __expf(m - mn) + so * __expf(mo - mn);
    m = mn;
  }
  float rden = 1.f / (sum + 1e-16f);  // per-lane: head j&3

  // phase B: lanes compute alpha for 16 edges x 4 heads in parallel,
  // then unrolled 16-step gather-fma (lane j = output channel, head j>>4)
  int hb = j >> 4;
  float acc = 0.f;
  int i0 = 0;
  for (; i0 + 16 <= deg; i0 += 16) {
    int s_j = ss[base + i0 + (j >> 2)];
    float e = a_src[(size_t)s_j * NH + h1] + adr;
    e = e > 0.f ? e : NEG_SLOPE * e;
    float al = __expf(e - m) * rden;
#pragma unroll
    for (int k = 0; k < 16; ++k) {
      int s = __shfl(s_j, k * 4, 64);
      float alpha = __shfl(al, k * 4 + hb, 64);
      acc += alpha * xw[(size_t)s * HC + j];
    }
  }
  int rem = deg - i0;
  if (rem > 0) {
    int ii = i0 + (j >> 2);
    int s_j = ss[base + (ii < deg ? ii : deg - 1)];
    float e = a_src[(size_t)s_j * NH + h1] + adr;
    e = e > 0.f ? e : NEG_SLOPE * e;
    float al = (ii < deg) ? __expf(e - m) * rden : 0.f;
    for (int k = 0; k < rem; ++k) {
      int s = __shfl(s_j, k * 4, 64);
      float alpha = __shfl(al, k * 4 + hb, 64);
      acc += alpha * xw[(size_t)s * HC + j];
    }
  }
  out[(size_t)d * HC + j] = acc + bias[j];
}

extern "C" void kernel_launch(void* const* d_in, const int* in_sizes, int n_in,
                              void* d_out, int out_size, void* d_ws, size_t ws_size,
                              hipStream_t stream) {
  const float* x       = (const float*)d_in[0];
  const int*   ei      = (const int*)d_in[1];
  // d_in[2] = edge_attr: ignored by the reference layer
  const float* W       = (const float*)d_in[3];
  const float* att_src = (const float*)d_in[4];
  const float* att_dst = (const float*)d_in[5];
  const float* bias    = (const float*)d_in[6];
  float* out = (float*)d_out;

  char* p = (char*)d_ws;
  float* xw     = (float*)p; p += (size_t)NN * HC * 4;   // 12.8 MB
  float* a_src  = (float*)p; p += (size_t)NN * NH * 4;   // 0.8 MB
  float* a_dst  = (float*)p; p += (size_t)NN * NH * 4;   // 0.8 MB
  int*   deg    = (int*)p;   p += (size_t)NN * 4;        // 0.2 MB
  int*   ptr    = (int*)p;   p += (size_t)(NN + 1) * 4;  // 0.2 MB
  int*   cursor = (int*)p;   p += (size_t)NN * 4;        // 0.2 MB
  int*   bsum   = (int*)p;   p += (size_t)NBLK * 4;      // tiny
  int*   ss     = (int*)p;   p += (size_t)NET * 4;       // 3.4 MB

  k_init<<<(NN + 255) / 256, 256, 0, stream>>>(deg, cursor);
  k_xw<<<NN / 16, 256, 0, stream>>>(x, W, att_src, att_dst, xw, a_src, a_dst);
  k_hist<<<(NET + 255) / 256, 256, 0, stream>>>(ei, deg);
  k_scan1<<<NBLK, 1024, 0, stream>>>(deg, ptr, bsum);
  k_scan2<<<NBLK, 1024, 0, stream>>>(bsum, ptr);
  k_scatter<<<(NET + 255) / 256, 256, 0, stream>>>(ei, ptr, cursor, ss);
  k_gat<<<(NN + 3) / 4, 256, 0, stream>>>(ptr, ss, a_src, a_dst, xw, bias, out);
}

// Round 6
// 177.598 us; speedup vs baseline: 19.5164x; 1.0648x over previous
//
#include <hip/hip_runtime.h>

// GATConv: N=50000, NIN=128, H=4, C=16 (HC=64), E=800000 (+N self-loops,
// synthesized inside k_gat rather than materialized in the CSR)
#define NN 50000
#define NIN 128
#define NH 4
#define NC 16
#define HC 64
#define NE 800000
#define NEG_SLOPE 0.2f
#define RPB 32                       // rows per block in k_xw
#define NBLK ((NN + 1023) / 1024)    // 49 scan blocks

// xw = x @ W (Ws in LDS, 32 rows/block, 8 rows/thread), attention dots fused.
// Also zeroes deg[] (free ride; k_hist runs strictly after on the same stream).
__global__ __launch_bounds__(256, 4) void k_xw(
    const float* __restrict__ x, const float* __restrict__ W,
    const float* __restrict__ att_src, const float* __restrict__ att_dst,
    float* __restrict__ xw, float* __restrict__ a_src, float* __restrict__ a_dst,
    int* __restrict__ deg) {
  __shared__ float Ws[NIN][HC];   // 32 KB
  __shared__ float xs[RPB][NIN];  // 16 KB
  int tid = threadIdx.x;
  int gi = blockIdx.x * 256 + tid;
  if (gi < NN) deg[gi] = 0;
  int row0 = blockIdx.x * RPB;
  int nrow = min(RPB, NN - row0);
  {
    const float4* wsrc = (const float4*)W;
    float4* wdst = (float4*)&Ws[0][0];
    for (int i = tid; i < NIN * HC / 4; i += 256) wdst[i] = wsrc[i];
    const float4* xsrc = (const float4*)(x + (size_t)row0 * NIN);
    float4* xdst = (float4*)&xs[0][0];
    for (int i = tid; i < nrow * (NIN / 4); i += 256) xdst[i] = xsrc[i];
  }
  __syncthreads();
  int j = tid & 63;
  int r8 = (tid >> 6) * 8;  // this wave's 8 rows
  float acc[8] = {0.f, 0.f, 0.f, 0.f, 0.f, 0.f, 0.f, 0.f};
#pragma unroll 2
  for (int k0 = 0; k0 < NIN; k0 += 4) {
    float w0 = Ws[k0 + 0][j], w1 = Ws[k0 + 1][j];
    float w2 = Ws[k0 + 2][j], w3 = Ws[k0 + 3][j];
#pragma unroll
    for (int r = 0; r < 8; ++r) {
      float4 xv = *(const float4*)&xs[r8 + r][k0];
      acc[r] += xv.x * w0 + xv.y * w1 + xv.z * w2 + xv.w * w3;
    }
  }
  int h = j >> 4, c = j & 15;
  float as = att_src[h * NC + c], ad = att_dst[h * NC + c];
#pragma unroll
  for (int r = 0; r < 8; ++r) {
    int lr = r8 + r;
    int gr = row0 + lr;
    float v = acc[r];
    float ps = v * as, pd = v * ad;
#pragma unroll
    for (int off = 8; off >= 1; off >>= 1) {
      ps += __shfl_xor(ps, off, 64);
      pd += __shfl_xor(pd, off, 64);
    }
    if (lr < nrow) {
      xw[(size_t)gr * HC + j] = v;
      if (c == 0) {
        a_src[gr * NH + h] = ps;
        a_dst[gr * NH + h] = pd;
      }
    }
  }
}

// histogram of destination degrees (real edges only), int4 vectorized
__global__ void k_hist(const int* __restrict__ ei, int* __restrict__ deg) {
  int i = blockIdx.x * blockDim.x + threadIdx.x;
  if (i >= NE / 4) return;
  int4 d4 = ((const int4*)(ei + NE))[i];
  atomicAdd(&deg[d4.x], 1);
  atomicAdd(&deg[d4.y], 1);
  atomicAdd(&deg[d4.z], 1);
  atomicAdd(&deg[d4.w], 1);
}

// hierarchical scan, level 1: per-block exclusive prefix + block totals
__global__ __launch_bounds__(1024) void k_scan1(const int* __restrict__ deg,
                                                int* __restrict__ ptr,
                                                int* __restrict__ bsum) {
  int t = threadIdx.x, b = blockIdx.x;
  int i = b * 1024 + t;
  int v = (i < NN) ? deg[i] : 0;
  int lane = t & 63, wid = t >> 6;
  int sv = v;
#pragma unroll
  for (int off = 1; off < 64; off <<= 1) {
    int n = __shfl_up(sv, off, 64);
    if (lane >= off) sv += n;
  }
  __shared__ int wsum[16];
  if (lane == 63) wsum[wid] = sv;
  __syncthreads();
  if (t < 16) {
    int w = wsum[t];
    int sw = w;
#pragma unroll
    for (int off = 1; off < 16; off <<= 1) {
      int n = __shfl_up(sw, off, 64);
      if (t >= off) sw += n;
    }
    wsum[t] = sw - w;           // exclusive wave offset
    if (t == 15) bsum[b] = sw;  // block total
  }
  __syncthreads();
  if (i < NN) ptr[i] = wsum[wid] + sv - v;
}

// level 2: add block offsets; also emit cur[] (scatter cursor = ptr copy)
__global__ __launch_bounds__(1024) void k_scan2(const int* __restrict__ bsum,
                                                int* __restrict__ ptr,
                                                int* __restrict__ cur) {
  int t = threadIdx.x, b = blockIdx.x;
  __shared__ int off_s, tot_s;
  if (t < 64) {
    int v = (t < NBLK) ? bsum[t] : 0;
    int sv = v;
#pragma unroll
    for (int off = 1; off < 64; off <<= 1) {
      int n = __shfl_up(sv, off, 64);
      if (t >= off) sv += n;
    }
    if (t == b) off_s = sv - v;     // exclusive prefix for this block
    if (t == NBLK - 1) tot_s = sv;  // grand total
  }
  __syncthreads();
  int i = b * 1024 + t;
  if (i < NN) {
    int v = ptr[i] + off_s;
    ptr[i] = v;
    cur[i] = v;
  }
  if (i == NN - 1) ptr[NN] = tot_s;
}

// scatter src ids into dst-sorted order; cur holds absolute positions
__global__ void k_scatter(const int* __restrict__ ei, int* __restrict__ cur,
                          int* __restrict__ ss) {
  int i = blockIdx.x * blockDim.x + threadIdx.x;
  if (i >= NE / 2) return;
  int2 s2 = ((const int2*)ei)[i];
  int2 d2 = ((const int2*)(ei + NE))[i];
  ss[atomicAdd(&cur[d2.x], 1)] = s2.x;
  ss[atomicAdd(&cur[d2.y], 1)] = s2.y;
}

// one wave per destination node: single-sweep online softmax + aggregation.
// Lane layout head-major: lane j = head (j>>4) x slot (j&15).
__global__ __launch_bounds__(256) void k_gat(
    const int* __restrict__ ptr, const int* __restrict__ ss,
    const float* __restrict__ a_src, const float* __restrict__ a_dst,
    const float* __restrict__ xw, const float* __restrict__ bias,
    float* __restrict__ out) {
  int tid = threadIdx.x;
  int wv = tid >> 6, j = tid & 63;
  int d = blockIdx.x * 4 + wv;
  if (d >= NN) return;
  int h = j >> 4, sl = j & 15;
  int base = ptr[d], deg = ptr[d + 1] - base;

  float adr = a_dst[(size_t)d * NH + h];
  float es = a_src[(size_t)d * NH + h] + adr;  // self-loop score
  es = es > 0.f ? es : NEG_SLOPE * es;
  float m = es;                        // running max (uniform per head group)
  float lpart = (sl == 0) ? 1.f : 0.f; // per-lane partial sum; self weight=1
  float acc = xw[(size_t)d * HC + j];  // self contribution (weight 1 at m=es)

  for (int i0 = 0; i0 < deg; i0 += 16) {
    int nb = min(16, deg - i0);
    int s_j = 0;
    float e = -1e30f;
    if (sl < nb) {
      s_j = ss[base + i0 + sl];
      e = a_src[(size_t)s_j * NH + h] + adr;
      e = e > 0.f ? e : NEG_SLOPE * e;
    }
    // block max within 16-lane head group
    float bm = e;
#pragma unroll
    for (int off = 8; off >= 1; off >>= 1) bm = fmaxf(bm, __shfl_xor(bm, off, 64));
    float mn = fmaxf(m, bm);
    float scale = __expf(m - mn);
    m = mn;
    acc *= scale;
    lpart *= scale;
    float al = (sl < nb) ? __expf(e - mn) : 0.f;
    lpart += al;
    if (nb == 16) {
#pragma unroll
      for (int k = 0; k < 16; ++k) {
        int s = __builtin_amdgcn_readlane(s_j, k);  // groups replicate -> uniform
        float alpha = __shfl(al, k, 16);
        acc += alpha * xw[(size_t)s * HC + j];
      }
    } else {
      for (int k = 0; k < nb; ++k) {
        int s = __shfl(s_j, k, 16);
        float alpha = __shfl(al, k, 16);
        acc += alpha * xw[(size_t)s * HC + j];
      }
    }
  }
  float L = lpart;
#pragma unroll
  for (int off = 8; off >= 1; off >>= 1) L += __shfl_xor(L, off, 64);
  out[(size_t)d * HC + j] = acc / (L + 1e-16f) + bias[j];
}

extern "C" void kernel_launch(void* const* d_in, const int* in_sizes, int n_in,
                              void* d_out, int out_size, void* d_ws, size_t ws_size,
                              hipStream_t stream) {
  const float* x       = (const float*)d_in[0];
  const int*   ei      = (const int*)d_in[1];
  // d_in[2] = edge_attr: ignored by the reference layer
  const float* W       = (const float*)d_in[3];
  const float* att_src = (const float*)d_in[4];
  const float* att_dst = (const float*)d_in[5];
  const float* bias    = (const float*)d_in[6];
  float* out = (float*)d_out;

  char* p = (char*)d_ws;
  float* xw     = (float*)p; p += (size_t)NN * HC * 4;   // 12.8 MB
  float* a_src  = (float*)p; p += (size_t)NN * NH * 4;   // 0.8 MB
  float* a_dst  = (float*)p; p += (size_t)NN * NH * 4;   // 0.8 MB
  int*   deg    = (int*)p;   p += (size_t)NN * 4;        // 0.2 MB
  int*   ptr    = (int*)p;   p += (size_t)(NN + 1) * 4;  // 0.2 MB
  int*   cur    = (int*)p;   p += (size_t)NN * 4;        // 0.2 MB
  int*   bsum   = (int*)p;   p += (size_t)NBLK * 4;      // tiny
  int*   ss     = (int*)p;   p += (size_t)NE * 4;        // 3.2 MB

  k_xw<<<(NN + RPB - 1) / RPB, 256, 0, stream>>>(x, W, att_src, att_dst,
                                                 xw, a_src, a_dst, deg);
  k_hist<<<(NE / 4 + 255) / 256, 256, 0, stream>>>(ei, deg);
  k_scan1<<<NBLK, 1024, 0, stream>>>(deg, ptr, bsum);
  k_scan2<<<NBLK, 1024, 0, stream>>>(bsum, ptr, cur);
  k_scatter<<<(NE / 2 + 255) / 256, 256, 0, stream>>>(ei, cur, ss);
  k_gat<<<(NN + 3) / 4, 256, 0, stream>>>(ptr, ss, a_src, a_dst, xw, bias, out);
}

// Round 7
// 169.714 us; speedup vs baseline: 20.4230x; 1.0465x over previous
//
#include <hip/hip_runtime.h>

// GATConv: N=50000, NIN=128, H=4, C=16 (HC=64), E=800000 (+N self-loops,
// synthesized inside k_gat rather than materialized in the CSR)
#define NN 50000
#define NIN 128
#define NH 4
#define NC 16
#define HC 64
#define NE 800000
#define NEG_SLOPE 0.2f
#define RPB 32                       // rows per block in k_xw
#define NBLK ((NN + 1023) / 1024)    // 49 scan blocks
#define NPART 8                      // dst partitions (== XCD count)
#define SCHUNK 128                   // blocks per partition in k_scatter
#define DPP (NN / NPART)             // 6250 dst per partition

// xw = x @ W (Ws in LDS, 32 rows/block, 8 rows/thread), attention dots fused.
// Also zeroes deg[] (free ride; k_hist runs strictly after on the same stream).
__global__ __launch_bounds__(256, 4) void k_xw(
    const float* __restrict__ x, const float* __restrict__ W,
    const float* __restrict__ att_src, const float* __restrict__ att_dst,
    float* __restrict__ xw, float* __restrict__ a_src, float* __restrict__ a_dst,
    int* __restrict__ deg) {
  __shared__ float Ws[NIN][HC];   // 32 KB
  __shared__ float xs[RPB][NIN];  // 16 KB
  int tid = threadIdx.x;
  int gi = blockIdx.x * 256 + tid;
  if (gi < NN) deg[gi] = 0;
  int row0 = blockIdx.x * RPB;
  int nrow = min(RPB, NN - row0);
  {
    const float4* wsrc = (const float4*)W;
    float4* wdst = (float4*)&Ws[0][0];
    for (int i = tid; i < NIN * HC / 4; i += 256) wdst[i] = wsrc[i];
    const float4* xsrc = (const float4*)(x + (size_t)row0 * NIN);
    float4* xdst = (float4*)&xs[0][0];
    for (int i = tid; i < nrow * (NIN / 4); i += 256) xdst[i] = xsrc[i];
  }
  __syncthreads();
  int j = tid & 63;
  int r8 = (tid >> 6) * 8;  // this wave's 8 rows
  float acc[8] = {0.f, 0.f, 0.f, 0.f, 0.f, 0.f, 0.f, 0.f};
#pragma unroll 2
  for (int k0 = 0; k0 < NIN; k0 += 4) {
    float w0 = Ws[k0 + 0][j], w1 = Ws[k0 + 1][j];
    float w2 = Ws[k0 + 2][j], w3 = Ws[k0 + 3][j];
#pragma unroll
    for (int r = 0; r < 8; ++r) {
      float4 xv = *(const float4*)&xs[r8 + r][k0];
      acc[r] += xv.x * w0 + xv.y * w1 + xv.z * w2 + xv.w * w3;
    }
  }
  int h = j >> 4, c = j & 15;
  float as = att_src[h * NC + c], ad = att_dst[h * NC + c];
#pragma unroll
  for (int r = 0; r < 8; ++r) {
    int lr = r8 + r;
    int gr = row0 + lr;
    float v = acc[r];
    float ps = v * as, pd = v * ad;
#pragma unroll
    for (int off = 8; off >= 1; off >>= 1) {
      ps += __shfl_xor(ps, off, 64);
      pd += __shfl_xor(pd, off, 64);
    }
    if (lr < nrow) {
      xw[(size_t)gr * HC + j] = v;
      if (c == 0) {
        a_src[gr * NH + h] = ps;
        a_dst[gr * NH + h] = pd;
      }
    }
  }
}

// histogram of destination degrees (real edges only), int4 vectorized
__global__ void k_hist(const int* __restrict__ ei, int* __restrict__ deg) {
  int i = blockIdx.x * blockDim.x + threadIdx.x;
  if (i >= NE / 4) return;
  int4 d4 = ((const int4*)(ei + NE))[i];
  atomicAdd(&deg[d4.x], 1);
  atomicAdd(&deg[d4.y], 1);
  atomicAdd(&deg[d4.z], 1);
  atomicAdd(&deg[d4.w], 1);
}

// hierarchical scan, level 1: per-block exclusive prefix + block totals
__global__ __launch_bounds__(1024) void k_scan1(const int* __restrict__ deg,
                                                int* __restrict__ ptr,
                                                int* __restrict__ bsum) {
  int t = threadIdx.x, b = blockIdx.x;
  int i = b * 1024 + t;
  int v = (i < NN) ? deg[i] : 0;
  int lane = t & 63, wid = t >> 6;
  int sv = v;
#pragma unroll
  for (int off = 1; off < 64; off <<= 1) {
    int n = __shfl_up(sv, off, 64);
    if (lane >= off) sv += n;
  }
  __shared__ int wsum[16];
  if (lane == 63) wsum[wid] = sv;
  __syncthreads();
  if (t < 16) {
    int w = wsum[t];
    int sw = w;
#pragma unroll
    for (int off = 1; off < 16; off <<= 1) {
      int n = __shfl_up(sw, off, 64);
      if (t >= off) sw += n;
    }
    wsum[t] = sw - w;           // exclusive wave offset
    if (t == 15) bsum[b] = sw;  // block total
  }
  __syncthreads();
  if (i < NN) ptr[i] = wsum[wid] + sv - v;
}

// level 2: add block offsets; also emit cur[] (scatter cursor = ptr copy)
__global__ __launch_bounds__(1024) void k_scan2(const int* __restrict__ bsum,
                                                int* __restrict__ ptr,
                                                int* __restrict__ cur) {
  int t = threadIdx.x, b = blockIdx.x;
  __shared__ int off_s, tot_s;
  if (t < 64) {
    int v = (t < NBLK) ? bsum[t] : 0;
    int sv = v;
#pragma unroll
    for (int off = 1; off < 64; off <<= 1) {
      int n = __shfl_up(sv, off, 64);
      if (t >= off) sv += n;
    }
    if (t == b) off_s = sv - v;     // exclusive prefix for this block
    if (t == NBLK - 1) tot_s = sv;  // grand total
  }
  __syncthreads();
  int i = b * 1024 + t;
  if (i < NN) {
    int v = ptr[i] + off_s;
    ptr[i] = v;
    cur[i] = v;
  }
  if (i == NN - 1) ptr[NN] = tot_s;
}

// dst-partitioned scatter: block b serves partition (b & 7); round-robin XCD
// dispatch keeps each ss region in ONE XCD's L2, so 4B scatter writes fill
// lines before writeback (was 16x write amplification, 53MB for 3.2MB payload).
__global__ __launch_bounds__(256) void k_scatter(const int* __restrict__ ei,
                                                 int* __restrict__ cur,
                                                 int* __restrict__ ss) {
  int p = blockIdx.x & (NPART - 1);
  int chunk = blockIdx.x >> 3;  // 0..SCHUNK-1
  int dlo = p * DPP, dhi = dlo + DPP;
  const int4* s4p = (const int4*)ei;
  const int4* d4p = (const int4*)(ei + NE);
  const int ngroups = NE / 4;  // 200000
  for (int g = chunk * 256 + threadIdx.x; g < ngroups; g += SCHUNK * 256) {
    int4 d4 = d4p[g];
    int4 s4 = s4p[g];
    if (d4.x >= dlo && d4.x < dhi) ss[atomicAdd(&cur[d4.x], 1)] = s4.x;
    if (d4.y >= dlo && d4.y < dhi) ss[atomicAdd(&cur[d4.y], 1)] = s4.y;
    if (d4.z >= dlo && d4.z < dhi) ss[atomicAdd(&cur[d4.z], 1)] = s4.z;
    if (d4.w >= dlo && d4.w < dhi) ss[atomicAdd(&cur[d4.w], 1)] = s4.w;
  }
}

// one wave per destination node: single-sweep online softmax + aggregation.
// Lane layout head-major: lane j = head (j>>4) x slot (j&15).
__global__ __launch_bounds__(256) void k_gat(
    const int* __restrict__ ptr, const int* __restrict__ ss,
    const float* __restrict__ a_src, const float* __restrict__ a_dst,
    const float* __restrict__ xw, const float* __restrict__ bias,
    float* __restrict__ out) {
  int tid = threadIdx.x;
  int wv = tid >> 6, j = tid & 63;
  int d = blockIdx.x * 4 + wv;
  if (d >= NN) return;
  int h = j >> 4, sl = j & 15;
  int base = ptr[d], deg = ptr[d + 1] - base;

  float adr = a_dst[(size_t)d * NH + h];
  float es = a_src[(size_t)d * NH + h] + adr;  // self-loop score
  es = es > 0.f ? es : NEG_SLOPE * es;
  float m = es;                        // running max (uniform per head group)
  float lpart = (sl == 0) ? 1.f : 0.f; // per-lane partial sum; self weight=1
  float acc = xw[(size_t)d * HC + j];  // self contribution (weight 1 at m=es)

  for (int i0 = 0; i0 < deg; i0 += 16) {
    int nb = min(16, deg - i0);
    int s_j = 0;
    float e = -1e30f;
    if (sl < nb) {
      s_j = ss[base + i0 + sl];
      e = a_src[(size_t)s_j * NH + h] + adr;
      e = e > 0.f ? e : NEG_SLOPE * e;
    }
    // block max within 16-lane head group
    float bm = e;
#pragma unroll
    for (int off = 8; off >= 1; off >>= 1) bm = fmaxf(bm, __shfl_xor(bm, off, 64));
    float mn = fmaxf(m, bm);
    float scale = __expf(m - mn);
    m = mn;
    acc *= scale;
    lpart *= scale;
    float al = (sl < nb) ? __expf(e - mn) : 0.f;
    lpart += al;
    if (nb == 16) {
#pragma unroll
      for (int k = 0; k < 16; ++k) {
        int s = __builtin_amdgcn_readlane(s_j, k);  // groups replicate -> uniform
        float alpha = __shfl(al, k, 16);
        acc += alpha * xw[(size_t)s * HC + j];
      }
    } else {
      for (int k = 0; k < nb; ++k) {
        int s = __shfl(s_j, k, 16);
        float alpha = __shfl(al, k, 16);
        acc += alpha * xw[(size_t)s * HC + j];
      }
    }
  }
  float L = lpart;
#pragma unroll
  for (int off = 8; off >= 1; off >>= 1) L += __shfl_xor(L, off, 64);
  out[(size_t)d * HC + j] = acc / (L + 1e-16f) + bias[j];
}

extern "C" void kernel_launch(void* const* d_in, const int* in_sizes, int n_in,
                              void* d_out, int out_size, void* d_ws, size_t ws_size,
                              hipStream_t stream) {
  const float* x       = (const float*)d_in[0];
  const int*   ei      = (const int*)d_in[1];
  // d_in[2] = edge_attr: ignored by the reference layer
  const float* W       = (const float*)d_in[3];
  const float* att_src = (const float*)d_in[4];
  const float* att_dst = (const float*)d_in[5];
  const float* bias    = (const float*)d_in[6];
  float* out = (float*)d_out;

  char* p = (char*)d_ws;
  float* xw     = (float*)p; p += (size_t)NN * HC * 4;   // 12.8 MB
  float* a_src  = (float*)p; p += (size_t)NN * NH * 4;   // 0.8 MB
  float* a_dst  = (float*)p; p += (size_t)NN * NH * 4;   // 0.8 MB
  int*   deg    = (int*)p;   p += (size_t)NN * 4;        // 0.2 MB
  int*   ptr    = (int*)p;   p += (size_t)(NN + 1) * 4;  // 0.2 MB
  int*   cur    = (int*)p;   p += (size_t)NN * 4;        // 0.2 MB
  int*   bsum   = (int*)p;   p += (size_t)NBLK * 4;      // tiny
  int*   ss     = (int*)p;   p += (size_t)NE * 4;        // 3.2 MB

  k_xw<<<(NN + RPB - 1) / RPB, 256, 0, stream>>>(x, W, att_src, att_dst,
                                                 xw, a_src, a_dst, deg);
  k_hist<<<(NE / 4 + 255) / 256, 256, 0, stream>>>(ei, deg);
  k_scan1<<<NBLK, 1024, 0, stream>>>(deg, ptr, bsum);
  k_scan2<<<NBLK, 1024, 0, stream>>>(bsum, ptr, cur);
  k_scatter<<<NPART * SCHUNK, 256, 0, stream>>>(ei, cur, ss);
  k_gat<<<(NN + 3) / 4, 256, 0, stream>>>(ptr, ss, a_src, a_dst, xw, bias, out);
}

// Round 8
// 163.231 us; speedup vs baseline: 21.2342x; 1.0397x over previous
//
#include <hip/hip_runtime.h>

// GATConv: N=50000, NIN=128, H=4, C=16 (HC=64), E=800000 (+N self-loops,
// synthesized inside k_gat rather than materialized in the CSR)
#define NN 50000
#define NIN 128
#define NH 4
#define NC 16
#define HC 64
#define NE 800000
#define NEG_SLOPE 0.2f
#define RPB 16                       // rows per block in k_xw (LDS 40KB -> 4 blk/CU)
#define NBLK ((NN + 1023) / 1024)    // 49 scan blocks
#define NPART 8                      // dst partitions (== XCD count)
#define SCHUNK 128                   // blocks per partition in k_scatter
#define HCHUNK 64                    // blocks per partition in k_hist
#define DPP (NN / NPART)             // 6250 dst per partition

__device__ __forceinline__ ushort f2bf(float v) {  // RNE f32->bf16
  unsigned u = __float_as_uint(v);
  return (ushort)((u + 0x7FFFu + ((u >> 16) & 1u)) >> 16);
}
__device__ __forceinline__ float bf2f(ushort b) {
  return __uint_as_float((unsigned)b << 16);
}

// xw(bf16) = x @ W (Ws+xs in LDS, 16 rows/block, 4 rows/thread), att dots fused.
// Also zeroes deg[] (free ride; k_hist runs strictly after on the same stream).
__global__ __launch_bounds__(256, 4) void k_xw(
    const float* __restrict__ x, const float* __restrict__ W,
    const float* __restrict__ att_src, const float* __restrict__ att_dst,
    ushort* __restrict__ xwb, float* __restrict__ a_src, float* __restrict__ a_dst,
    int* __restrict__ deg) {
  __shared__ float Ws[NIN][HC];   // 32 KB
  __shared__ float xs[RPB][NIN];  // 8 KB
  int tid = threadIdx.x;
  int gi = blockIdx.x * 256 + tid;
  if (gi < NN) deg[gi] = 0;
  int row0 = blockIdx.x * RPB;  // NN % RPB == 0
  {
    const float4* wsrc = (const float4*)W;
    float4* wdst = (float4*)&Ws[0][0];
    for (int i = tid; i < NIN * HC / 4; i += 256) wdst[i] = wsrc[i];
    const float4* xsrc = (const float4*)(x + (size_t)row0 * NIN);
    float4* xdst = (float4*)&xs[0][0];
    for (int i = tid; i < RPB * (NIN / 4); i += 256) xdst[i] = xsrc[i];
  }
  __syncthreads();
  int j = tid & 63;
  int r4 = (tid >> 6) * 4;  // this wave's 4 rows
  float acc[4] = {0.f, 0.f, 0.f, 0.f};
#pragma unroll 2
  for (int k0 = 0; k0 < NIN; k0 += 4) {
    float w0 = Ws[k0 + 0][j], w1 = Ws[k0 + 1][j];
    float w2 = Ws[k0 + 2][j], w3 = Ws[k0 + 3][j];
#pragma unroll
    for (int r = 0; r < 4; ++r) {
      float4 xv = *(const float4*)&xs[r4 + r][k0];
      acc[r] += xv.x * w0 + xv.y * w1 + xv.z * w2 + xv.w * w3;
    }
  }
  int h = j >> 4, c = j & 15;
  float as = att_src[h * NC + c], ad = att_dst[h * NC + c];
#pragma unroll
  for (int r = 0; r < 4; ++r) {
    int gr = row0 + r4 + r;
    float v = acc[r];
    float ps = v * as, pd = v * ad;
#pragma unroll
    for (int off = 8; off >= 1; off >>= 1) {
      ps += __shfl_xor(ps, off, 64);
      pd += __shfl_xor(pd, off, 64);
    }
    xwb[(size_t)gr * HC + j] = f2bf(v);
    if (c == 0) {
      a_src[gr * NH + h] = ps;
      a_dst[gr * NH + h] = pd;
    }
  }
}

// XCD-affine partitioned histogram: block b serves dst range (b&7); the deg
// region stays in one XCD's L2 (atomic RMW lines don't bounce cross-XCD).
__global__ __launch_bounds__(256) void k_hist(const int* __restrict__ ei,
                                              int* __restrict__ deg) {
  int p = blockIdx.x & (NPART - 1);
  int chunk = blockIdx.x >> 3;
  int dlo = p * DPP, dhi = dlo + DPP;
  const int4* d4p = (const int4*)(ei + NE);
  const int ngroups = NE / 4;
  for (int g = chunk * 256 + threadIdx.x; g < ngroups; g += HCHUNK * 256) {
    int4 d4 = d4p[g];
    if (d4.x >= dlo && d4.x < dhi) atomicAdd(&deg[d4.x], 1);
    if (d4.y >= dlo && d4.y < dhi) atomicAdd(&deg[d4.y], 1);
    if (d4.z >= dlo && d4.z < dhi) atomicAdd(&deg[d4.z], 1);
    if (d4.w >= dlo && d4.w < dhi) atomicAdd(&deg[d4.w], 1);
  }
}

// hierarchical scan, level 1: per-block exclusive prefix + block totals
__global__ __launch_bounds__(1024) void k_scan1(const int* __restrict__ deg,
                                                int* __restrict__ ptr,
                                                int* __restrict__ bsum) {
  int t = threadIdx.x, b = blockIdx.x;
  int i = b * 1024 + t;
  int v = (i < NN) ? deg[i] : 0;
  int lane = t & 63, wid = t >> 6;
  int sv = v;
#pragma unroll
  for (int off = 1; off < 64; off <<= 1) {
    int n = __shfl_up(sv, off, 64);
    if (lane >= off) sv += n;
  }
  __shared__ int wsum[16];
  if (lane == 63) wsum[wid] = sv;
  __syncthreads();
  if (t < 16) {
    int w = wsum[t];
    int sw = w;
#pragma unroll
    for (int off = 1; off < 16; off <<= 1) {
      int n = __shfl_up(sw, off, 64);
      if (t >= off) sw += n;
    }
    wsum[t] = sw - w;           // exclusive wave offset
    if (t == 15) bsum[b] = sw;  // block total
  }
  __syncthreads();
  if (i < NN) ptr[i] = wsum[wid] + sv - v;
}

// level 2: add block offsets; also emit cur[] (scatter cursor = ptr copy)
__global__ __launch_bounds__(1024) void k_scan2(const int* __restrict__ bsum,
                                                int* __restrict__ ptr,
                                                int* __restrict__ cur) {
  int t = threadIdx.x, b = blockIdx.x;
  __shared__ int off_s, tot_s;
  if (t < 64) {
    int v = (t < NBLK) ? bsum[t] : 0;
    int sv = v;
#pragma unroll
    for (int off = 1; off < 64; off <<= 1) {
      int n = __shfl_up(sv, off, 64);
      if (t >= off) sv += n;
    }
    if (t == b) off_s = sv - v;     // exclusive prefix for this block
    if (t == NBLK - 1) tot_s = sv;  // grand total
  }
  __syncthreads();
  int i = b * 1024 + t;
  if (i < NN) {
    int v = ptr[i] + off_s;
    ptr[i] = v;
    cur[i] = v;
  }
  if (i == NN - 1) ptr[NN] = tot_s;
}

// dst-partitioned scatter: block b serves partition (b & 7); round-robin XCD
// dispatch keeps each ss region in ONE XCD's L2, so 4B scatter writes fill
// lines before writeback (was 16x write amplification, 53MB for 3.2MB payload).
__global__ __launch_bounds__(256) void k_scatter(const int* __restrict__ ei,
                                                 int* __restrict__ cur,
                                                 int* __restrict__ ss) {
  int p = blockIdx.x & (NPART - 1);
  int chunk = blockIdx.x >> 3;  // 0..SCHUNK-1
  int dlo = p * DPP, dhi = dlo + DPP;
  const int4* s4p = (const int4*)ei;
  const int4* d4p = (const int4*)(ei + NE);
  const int ngroups = NE / 4;  // 200000
  for (int g = chunk * 256 + threadIdx.x; g < ngroups; g += SCHUNK * 256) {
    int4 d4 = d4p[g];
    int4 s4 = s4p[g];
    if (d4.x >= dlo && d4.x < dhi) ss[atomicAdd(&cur[d4.x], 1)] = s4.x;
    if (d4.y >= dlo && d4.y < dhi) ss[atomicAdd(&cur[d4.y], 1)] = s4.y;
    if (d4.z >= dlo && d4.z < dhi) ss[atomicAdd(&cur[d4.z], 1)] = s4.z;
    if (d4.w >= dlo && d4.w < dhi) ss[atomicAdd(&cur[d4.w], 1)] = s4.w;
  }
}

// one wave per destination node: single-sweep online softmax + aggregation.
// Lane layout head-major: lane j = head (j>>4) x slot (j&15). xw gathered bf16.
__global__ __launch_bounds__(256) void k_gat(
    const int* __restrict__ ptr, const int* __restrict__ ss,
    const float* __restrict__ a_src, const float* __restrict__ a_dst,
    const ushort* __restrict__ xwb, const float* __restrict__ bias,
    float* __restrict__ out) {
  int tid = threadIdx.x;
  int wv = tid >> 6, j = tid & 63;
  int d = blockIdx.x * 4 + wv;
  if (d >= NN) return;
  int h = j >> 4, sl = j & 15;
  int base = ptr[d], deg = ptr[d + 1] - base;

  float adr = a_dst[(size_t)d * NH + h];
  float es = a_src[(size_t)d * NH + h] + adr;  // self-loop score
  es = es > 0.f ? es : NEG_SLOPE * es;
  float m = es;                          // running max (uniform per head group)
  float lpart = (sl == 0) ? 1.f : 0.f;   // per-lane partial sum; self weight=1
  float acc = bf2f(xwb[(size_t)d * HC + j]);  // self contribution

  for (int i0 = 0; i0 < deg; i0 += 16) {
    int nb = min(16, deg - i0);
    int s_j = 0;
    float e = -1e30f;
    if (sl < nb) {
      s_j = ss[base + i0 + sl];
      e = a_src[(size_t)s_j * NH + h] + adr;
      e = e > 0.f ? e : NEG_SLOPE * e;
    }
    // block max within 16-lane head group
    float bm = e;
#pragma unroll
    for (int off = 8; off >= 1; off >>= 1) bm = fmaxf(bm, __shfl_xor(bm, off, 64));
    float mn = fmaxf(m, bm);
    float scale = __expf(m - mn);
    m = mn;
    acc *= scale;
    lpart *= scale;
    float al = (sl < nb) ? __expf(e - mn) : 0.f;
    lpart += al;
    if (nb == 16) {
#pragma unroll
      for (int k = 0; k < 16; ++k) {
        int s = __builtin_amdgcn_readlane(s_j, k);  // groups replicate -> uniform
        float alpha = __shfl(al, k, 16);
        acc += alpha * bf2f(xwb[(size_t)s * HC + j]);
      }
    } else {
      for (int k = 0; k < nb; ++k) {
        int s = __shfl(s_j, k, 16);
        float alpha = __shfl(al, k, 16);
        acc += alpha * bf2f(xwb[(size_t)s * HC + j]);
      }
    }
  }
  float L = lpart;
#pragma unroll
  for (int off = 8; off >= 1; off >>= 1) L += __shfl_xor(L, off, 64);
  out[(size_t)d * HC + j] = acc / (L + 1e-16f) + bias[j];
}

extern "C" void kernel_launch(void* const* d_in, const int* in_sizes, int n_in,
                              void* d_out, int out_size, void* d_ws, size_t ws_size,
                              hipStream_t stream) {
  const float* x       = (const float*)d_in[0];
  const int*   ei      = (const int*)d_in[1];
  // d_in[2] = edge_attr: ignored by the reference layer
  const float* W       = (const float*)d_in[3];
  const float* att_src = (const float*)d_in[4];
  const float* att_dst = (const float*)d_in[5];
  const float* bias    = (const float*)d_in[6];
  float* out = (float*)d_out;

  char* p = (char*)d_ws;
  ushort* xwb   = (ushort*)p; p += (size_t)NN * HC * 2;  // 6.4 MB (bf16)
  float* a_src  = (float*)p;  p += (size_t)NN * NH * 4;  // 0.8 MB
  float* a_dst  = (float*)p;  p += (size_t)NN * NH * 4;  // 0.8 MB
  int*   deg    = (int*)p;    p += (size_t)NN * 4;       // 0.2 MB
  int*   ptr    = (int*)p;    p += (size_t)(NN + 1) * 4; // 0.2 MB
  int*   cur    = (int*)p;    p += (size_t)NN * 4;       // 0.2 MB
  int*   bsum   = (int*)p;    p += (size_t)NBLK * 4;     // tiny
  int*   ss     = (int*)p;    p += (size_t)NE * 4;       // 3.2 MB

  k_xw<<<NN / RPB, 256, 0, stream>>>(x, W, att_src, att_dst,
                                     xwb, a_src, a_dst, deg);
  k_hist<<<NPART * HCHUNK, 256, 0, stream>>>(ei, deg);
  k_scan1<<<NBLK, 1024, 0, stream>>>(deg, ptr, bsum);
  k_scan2<<<NBLK, 1024, 0, stream>>>(bsum, ptr, cur);
  k_scatter<<<NPART * SCHUNK, 256, 0, stream>>>(ei, cur, ss);
  k_gat<<<(NN + 3) / 4, 256, 0, stream>>>(ptr, ss, a_src, a_dst, xwb, bias, out);
}